// Round 8
// baseline (35.639 us; speedup 1.0000x reference)
//
#include <hip/hip_runtime.h>
#include <math.h>

#define NPT 512
#define BROWS 4096
#define TAB_U4 18   // 18 uint4 slots per lane, SoA: tab[slot*64 + lane]

typedef _Float16 half8 __attribute__((ext_vector_type(8)));
typedef _Float16 h2    __attribute__((ext_vector_type(2)));
typedef float    f32x4 __attribute__((ext_vector_type(4)));
typedef unsigned int u32x4 __attribute__((ext_vector_type(4)));

__device__ __forceinline__ float sigmoidf_fast(float x) {
    return 1.0f / (1.0f + __expf(-x));
}

// ---------------- setup: build per-lane constant table (1 wave) ----------------
// Slot map (per lane): 0-3 Wf00/01/10/11 (half8); 4-11 w1pk[k][i] (32 h2);
// 12-13 b1pk (8 h2); 14 accInit0; 15 accInit1; 16 w3q0; 17 w3q1 (f32x4 each).
__global__ __launch_bounds__(64) void setup_kernel(
    const float* __restrict__ W1, const float* __restrict__ b1,
    const float* __restrict__ W2, const float* __restrict__ b2,
    const float* __restrict__ W3, u32x4* __restrict__ tab)
{
    const int lane = threadIdx.x & 63;
    const int nn   = lane & 15;
    const int kg   = lane >> 4;
    const int kg8  = kg * 8;

    half8 Wf00, Wf01, Wf10, Wf11;
    #pragma unroll
    for (int j = 0; j < 8; ++j) {
        Wf00[j] = (_Float16)W2[(0  + kg8 + j) * 32 + 0  + nn];
        Wf01[j] = (_Float16)W2[(0  + kg8 + j) * 32 + 16 + nn];
        Wf10[j] = (_Float16)W2[(32 + kg8 + j) * 32 + 0  + nn];
        Wf11[j] = (_Float16)W2[(32 + kg8 + j) * 32 + 16 + nn];
    }
    tab[0 * 64 + lane] = __builtin_bit_cast(u32x4, Wf00);
    tab[1 * 64 + lane] = __builtin_bit_cast(u32x4, Wf01);
    tab[2 * 64 + lane] = __builtin_bit_cast(u32x4, Wf10);
    tab[3 * 64 + lane] = __builtin_bit_cast(u32x4, Wf11);

    unsigned int wbuf[32], bbuf[8];
    #pragma unroll
    for (int i = 0; i < 8; ++i) {
        const int ch = (i < 4) ? (kg8 + 2 * i) : (32 + kg8 + 2 * (i - 4));
        #pragma unroll
        for (int k = 0; k < 4; ++k) {
            h2 v; v[0] = (_Float16)W1[k * 64 + ch]; v[1] = (_Float16)W1[k * 64 + ch + 1];
            wbuf[k * 8 + i] = __builtin_bit_cast(unsigned int, v);
        }
        h2 bv; bv[0] = (_Float16)b1[ch]; bv[1] = (_Float16)b1[ch + 1];
        bbuf[i] = __builtin_bit_cast(unsigned int, bv);
    }
    #pragma unroll
    for (int p = 0; p < 8; ++p) {
        u32x4 v;
        v[0] = wbuf[p * 4 + 0]; v[1] = wbuf[p * 4 + 1];
        v[2] = wbuf[p * 4 + 2]; v[3] = wbuf[p * 4 + 3];
        tab[(4 + p) * 64 + lane] = v;
    }
    {
        u32x4 v0, v1;
        #pragma unroll
        for (int e = 0; e < 4; ++e) { v0[e] = bbuf[e]; v1[e] = bbuf[4 + e]; }
        tab[12 * 64 + lane] = v0;
        tab[13 * 64 + lane] = v1;
    }
    f32x4 ai0, ai1, wq0, wq1;
    #pragma unroll
    for (int q = 0; q < 4; ++q) {
        const int ch = kg * 4 + q;
        ai0[q] = b2[ch];
        ai1[q] = b2[16 + ch];
        wq0[q] = W3[ch];
        wq1[q] = W3[16 + ch];
    }
    tab[14 * 64 + lane] = __builtin_bit_cast(u32x4, ai0);
    tab[15 * 64 + lane] = __builtin_bit_cast(u32x4, ai1);
    tab[16 * 64 + lane] = __builtin_bit_cast(u32x4, wq0);
    tab[17 * 64 + lane] = __builtin_bit_cast(u32x4, wq1);
}

// ---------------- main: 1 block = 2 rows = 4 waves ----------------
// Wave owns 128 points of each of 2 rows (4 independent 64-pt segments).
// Per segment the 4 q-chains are STAGED (all shfl -> all layer1 -> all MFMA ->
// all epilogue) with static indexing, forcing ~130 live VGPRs so the chains
// actually overlap. __launch_bounds__(256,3): VGPR cap ~170, 3 blocks/CU.
__global__ __launch_bounds__(256, 3) void wps_kernel(
    const float* __restrict__ wp,    // (B, N, 2)
    const float* __restrict__ sww,
    const float* __restrict__ b3,
    const u32x4* __restrict__ tab,
    float* __restrict__ out)
{
    __shared__ float sLg[2][NPT];    // raw logits, 4 KB

    const int t    = threadIdx.x;
    const int lane = t & 63;
    const int wv   = t >> 6;
    const int row0 = blockIdx.x * 2;

    const int nn = lane & 15;
    const int kg = lane >> 6 ? 0 : (lane >> 4);   // kg = lane>>4 (0..3)

    // ---- constants from table (coalesced vector loads) ----
    const half8 Wf00 = __builtin_bit_cast(half8, tab[0 * 64 + lane]);
    const half8 Wf01 = __builtin_bit_cast(half8, tab[1 * 64 + lane]);
    const half8 Wf10 = __builtin_bit_cast(half8, tab[2 * 64 + lane]);
    const half8 Wf11 = __builtin_bit_cast(half8, tab[3 * 64 + lane]);

    h2 w1pk[4][8];
    #pragma unroll
    for (int p = 0; p < 8; ++p) {
        u32x4 v = tab[(4 + p) * 64 + lane];
        #pragma unroll
        for (int e = 0; e < 4; ++e) {
            const int j = p * 4 + e;             // j = k*8 + i
            w1pk[j >> 3][j & 7] = __builtin_bit_cast(h2, (unsigned int)v[e]);
        }
    }
    h2 b1pk[8];
    {
        u32x4 v0 = tab[12 * 64 + lane];
        u32x4 v1 = tab[13 * 64 + lane];
        #pragma unroll
        for (int e = 0; e < 4; ++e) {
            b1pk[e]     = __builtin_bit_cast(h2, (unsigned int)v0[e]);
            b1pk[4 + e] = __builtin_bit_cast(h2, (unsigned int)v1[e]);
        }
    }
    const f32x4 accInit0 = __builtin_bit_cast(f32x4, tab[14 * 64 + lane]);
    const f32x4 accInit1 = __builtin_bit_cast(f32x4, tab[15 * 64 + lane]);
    const f32x4 w3q0v    = __builtin_bit_cast(f32x4, tab[16 * 64 + lane]);
    const f32x4 w3q1v    = __builtin_bit_cast(f32x4, tab[17 * 64 + lane]);

    const int seg = wv * 128;

    #pragma unroll
    for (int r = 0; r < 2; ++r) {
        const float2* P = (const float2*)(wp + (size_t)(row0 + r) * NPT * 2);

        #pragma unroll
        for (int s = 0; s < 2; ++s) {
            const int base = seg + s * 64;
            const int g    = base + lane;

            // ---- features for THIS lane's point, computed once (verified) ----
            float2 p  = P[g];
            float2 pm = P[(g > 0) ? g - 1 : 0];
            float2 pp = P[(g < NPT - 1) ? g + 1 : NPT - 1];
            float d1x, d1y;
            if (g < NPT - 1) { d1x = pp.x - p.x; d1y = pp.y - p.y; }
            else             { d1x = p.x - pm.x; d1y = p.y - pm.y; }
            float d2x = 0.f, d2y = 0.f;
            if (g >= 1 && g <= NPT - 2) {
                d2x = pp.x - 2.f * p.x + pm.x;
                d2y = pp.y - 2.f * p.y + pm.y;
            }
            h2 f01; f01[0] = (_Float16)d1x; f01[1] = (_Float16)d1y;
            h2 f23; f23[0] = (_Float16)d2x; f23[1] = (_Float16)d2y;
            const int u01 = __builtin_bit_cast(int, f01);
            const int u23 = __builtin_bit_cast(int, f23);

            // ---- stage A: all 4 q redistributions (8 shfl, independent) ----
            int ru01[4], ru23[4];
            #pragma unroll
            for (int q = 0; q < 4; ++q) {
                ru01[q] = __shfl(u01, q * 16 + nn);
                ru23[q] = __shfl(u23, q * 16 + nn);
            }

            // ---- stage B: all 4 q layer-1 fragment sets (verified math) ----
            union Frag { half8 v; h2 p[4]; };
            Frag H0[4], H1[4];
            #pragma unroll
            for (int q = 0; q < 4; ++q) {
                h2 r01 = __builtin_bit_cast(h2, ru01[q]);
                h2 r23 = __builtin_bit_cast(h2, ru23[q]);
                h2 f0; f0[0] = f0[1] = r01[0];
                h2 f1; f1[0] = f1[1] = r01[1];
                h2 f2; f2[0] = f2[1] = r23[0];
                h2 f3; f3[0] = f3[1] = r23[1];
                #pragma unroll
                for (int i = 0; i < 8; ++i) {
                    h2 h = b1pk[i];
                    h += f0 * w1pk[0][i];
                    h += f1 * w1pk[1][i];
                    h += f2 * w1pk[2][i];
                    h += f3 * w1pk[3][i];
                    h2 z; z[0] = (_Float16)0.f; z[1] = (_Float16)0.f;
                    h = __builtin_elementwise_max(h, z);
                    if (i < 4) H0[q].p[i] = h; else H1[q].p[i - 4] = h;
                }
            }

            // ---- stage C: all 16 MFMAs (verified swapped layout) ----
            f32x4 a0[4], a1[4];
            #pragma unroll
            for (int q = 0; q < 4; ++q) {
                f32x4 acc0 = accInit0;
                f32x4 acc1 = accInit1;
                acc0 = __builtin_amdgcn_mfma_f32_16x16x32_f16(Wf00, H0[q].v, acc0, 0, 0, 0);
                acc0 = __builtin_amdgcn_mfma_f32_16x16x32_f16(Wf10, H1[q].v, acc0, 0, 0, 0);
                acc1 = __builtin_amdgcn_mfma_f32_16x16x32_f16(Wf01, H0[q].v, acc1, 0, 0, 0);
                acc1 = __builtin_amdgcn_mfma_f32_16x16x32_f16(Wf11, H1[q].v, acc1, 0, 0, 0);
                a0[q] = acc0; a1[q] = acc1;
            }

            // ---- stage D: all 4 epilogues (tree reduce + 2 shfl_xor each) ----
            float vkeep = 0.f;
            #pragma unroll
            for (int q = 0; q < 4; ++q) {
                float va = 0.f, vb = 0.f;
                #pragma unroll
                for (int q2 = 0; q2 < 4; ++q2) {
                    va = fmaf(fmaxf(a0[q][q2], 0.f), w3q0v[q2], va);
                    vb = fmaf(fmaxf(a1[q][q2], 0.f), w3q1v[q2], vb);
                }
                float v = va + vb;
                v += __shfl_xor(v, 16);
                v += __shfl_xor(v, 32);
                if (q == kg) vkeep = v;
            }

            sLg[r][g] = vkeep;   // contiguous LDS store
        }
    }

    __syncthreads();

    // ---- scan: waves 0,1 handle rows 0,1 (verified round-4 body) ----
    if (wv < 2) {
        const int row = row0 + wv;
        const float2* P = (const float2*)(wp + (size_t)row * NPT * 2);
        const float bias3 = b3[0];
        const float swv   = sigmoidf_fast(sww[0]);

        const int base = lane * 8;
        float wr[8];
        *reinterpret_cast<float4*>(&wr[0]) = *reinterpret_cast<const float4*>(&sLg[wv][base]);
        *reinterpret_cast<float4*>(&wr[4]) = *reinterpret_cast<const float4*>(&sLg[wv][base + 4]);

        const float4* P4 = (const float4*)P;
        float2 pts[8];
        #pragma unroll
        for (int s = 0; s < 4; ++s) {
            float4 v = P4[lane * 4 + s];
            pts[2 * s].x     = v.x; pts[2 * s].y     = v.y;
            pts[2 * s + 1].x = v.z; pts[2 * s + 1].y = v.w;
        }

        float a8[8], cx8[8], cy8[8];
        float A = 1.f, Cx = 0.f, Cy = 0.f;
        #pragma unroll
        for (int i = 0; i < 8; ++i) {
            const int g = base + i;
            float a = (g == 0) ? 0.f
                               : swv * (1.f - sigmoidf_fast(wr[i] + bias3));
            float cx = (1.f - a) * pts[i].x;
            float cy = (1.f - a) * pts[i].y;
            a8[i] = a; cx8[i] = cx; cy8[i] = cy;
            Cx = fmaf(a, Cx, cx);
            Cy = fmaf(a, Cy, cy);
            A *= a;
        }
        #pragma unroll
        for (int d = 1; d < 64; d <<= 1) {
            float Ap  = __shfl_up(A, d);
            float Cpx = __shfl_up(Cx, d);
            float Cpy = __shfl_up(Cy, d);
            if (lane >= d) {
                Cx = fmaf(A, Cpx, Cx);
                Cy = fmaf(A, Cpy, Cy);
                A *= Ap;
            }
        }
        float yx = __shfl_up(Cx, 1);
        float yy = __shfl_up(Cy, 1);
        if (lane == 0) { yx = 0.f; yy = 0.f; }

        float2 pe = P[NPT - 1];
        float4* orow = (float4*)(out + (size_t)row * NPT * 2);
        #pragma unroll
        for (int s2 = 0; s2 < 4; ++s2) {
            float x0, y0v, x1, y1v;
            { const int i = 2 * s2;
              yx = fmaf(a8[i], yx, cx8[i]); yy = fmaf(a8[i], yy, cy8[i]);
              x0 = yx; y0v = yy; }
            { const int i = 2 * s2 + 1;
              yx = fmaf(a8[i], yx, cx8[i]); yy = fmaf(a8[i], yy, cy8[i]);
              x1 = yx; y1v = yy; }
            if (lane == 63 && s2 == 3) { x1 = pe.x; y1v = pe.y; }
            orow[lane * 4 + s2] = make_float4(x0, y0v, x1, y1v);
        }
    }
}

extern "C" void kernel_launch(void* const* d_in, const int* in_sizes, int n_in,
                              void* d_out, int out_size, void* d_ws, size_t ws_size,
                              hipStream_t stream) {
    const float* wp  = (const float*)d_in[0];
    const float* sww = (const float*)d_in[1];
    const float* W1  = (const float*)d_in[2];
    const float* b1  = (const float*)d_in[3];
    const float* W2  = (const float*)d_in[4];
    const float* b2  = (const float*)d_in[5];
    const float* W3  = (const float*)d_in[6];
    const float* b3  = (const float*)d_in[7];
    float* out = (float*)d_out;
    u32x4* tab = (u32x4*)d_ws;   // 18 KB used; ws is far larger

    setup_kernel<<<1, 64, 0, stream>>>(W1, b1, W2, b2, W3, tab);
    wps_kernel<<<BROWS / 2, 256, 0, stream>>>(wp, sww, b3, tab, out);
}

// Round 10
// 33.182 us; speedup vs baseline: 1.0740x; 1.0740x over previous
//
#include <hip/hip_runtime.h>
#include <math.h>

#define NPT 512
#define BROWS 4096
#define TAB_U4 17   // 17 uint4 slots per lane, SoA: tab[slot*64 + lane]

typedef _Float16 half8 __attribute__((ext_vector_type(8)));
typedef _Float16 h2    __attribute__((ext_vector_type(2)));
typedef float    f32x4 __attribute__((ext_vector_type(4)));
typedef unsigned int u32x4 __attribute__((ext_vector_type(4)));

__device__ __forceinline__ float sigmoidf_fast(float x) {
    return 1.0f / (1.0f + __expf(-x));
}

// cvt_pkrtz returns __fp16x2; bit-cast to our h2 (_Float16x2) — same bits.
__device__ __forceinline__ h2 pkrtz(float a, float b) {
    return __builtin_bit_cast(h2, __builtin_amdgcn_cvt_pkrtz(a, b));
}

#if __has_builtin(__builtin_amdgcn_fdot2)
__device__ __forceinline__ float fdot2(h2 a, h2 b, float c) {
    return __builtin_amdgcn_fdot2(__builtin_bit_cast(__fp16 __attribute__((ext_vector_type(2))), a),
                                  __builtin_bit_cast(__fp16 __attribute__((ext_vector_type(2))), b),
                                  c, false);
}
#else
__device__ __forceinline__ float fdot2(h2 a, h2 b, float c) {
    c = fmaf((float)a[0], (float)b[0], c);
    c = fmaf((float)a[1], (float)b[1], c);
    return c;
}
#endif

// ---------------- setup: build per-lane constant table (1 wave) ----------------
// Slots: 0-3 Wf00/01/10/11 (half8); 4-11 w1pk (32 h2); 12-13 b1pk (8 h2);
// 14 accInit0 (f32x4); 15 accInit1 (f32x4); 16 w3 packed as 4 h2 pairs.
__global__ __launch_bounds__(64) void setup_kernel(
    const float* __restrict__ W1, const float* __restrict__ b1,
    const float* __restrict__ W2, const float* __restrict__ b2,
    const float* __restrict__ W3, u32x4* __restrict__ tab)
{
    const int lane = threadIdx.x & 63;
    const int nn   = lane & 15;
    const int kg   = lane >> 4;
    const int kg8  = kg * 8;

    half8 Wf00, Wf01, Wf10, Wf11;
    #pragma unroll
    for (int j = 0; j < 8; ++j) {
        Wf00[j] = (_Float16)W2[(0  + kg8 + j) * 32 + 0  + nn];
        Wf01[j] = (_Float16)W2[(0  + kg8 + j) * 32 + 16 + nn];
        Wf10[j] = (_Float16)W2[(32 + kg8 + j) * 32 + 0  + nn];
        Wf11[j] = (_Float16)W2[(32 + kg8 + j) * 32 + 16 + nn];
    }
    tab[0 * 64 + lane] = __builtin_bit_cast(u32x4, Wf00);
    tab[1 * 64 + lane] = __builtin_bit_cast(u32x4, Wf01);
    tab[2 * 64 + lane] = __builtin_bit_cast(u32x4, Wf10);
    tab[3 * 64 + lane] = __builtin_bit_cast(u32x4, Wf11);

    unsigned int wbuf[32], bbuf[8];
    #pragma unroll
    for (int i = 0; i < 8; ++i) {
        const int ch = (i < 4) ? (kg8 + 2 * i) : (32 + kg8 + 2 * (i - 4));
        #pragma unroll
        for (int k = 0; k < 4; ++k) {
            h2 v; v[0] = (_Float16)W1[k * 64 + ch]; v[1] = (_Float16)W1[k * 64 + ch + 1];
            wbuf[k * 8 + i] = __builtin_bit_cast(unsigned int, v);
        }
        h2 bv; bv[0] = (_Float16)b1[ch]; bv[1] = (_Float16)b1[ch + 1];
        bbuf[i] = __builtin_bit_cast(unsigned int, bv);
    }
    #pragma unroll
    for (int p = 0; p < 8; ++p) {
        u32x4 v;
        v[0] = wbuf[p * 4 + 0]; v[1] = wbuf[p * 4 + 1];
        v[2] = wbuf[p * 4 + 2]; v[3] = wbuf[p * 4 + 3];
        tab[(4 + p) * 64 + lane] = v;
    }
    {
        u32x4 v0, v1;
        #pragma unroll
        for (int e = 0; e < 4; ++e) { v0[e] = bbuf[e]; v1[e] = bbuf[4 + e]; }
        tab[12 * 64 + lane] = v0;
        tab[13 * 64 + lane] = v1;
    }
    f32x4 ai0, ai1;
    u32x4 w3v;
    #pragma unroll
    for (int q = 0; q < 4; ++q) {
        const int ch = kg * 4 + q;
        ai0[q] = b2[ch];
        ai1[q] = b2[16 + ch];
    }
    #pragma unroll
    for (int e = 0; e < 2; ++e) {
        h2 a, b;
        a[0] = (_Float16)W3[kg * 4 + 2 * e];
        a[1] = (_Float16)W3[kg * 4 + 2 * e + 1];
        b[0] = (_Float16)W3[16 + kg * 4 + 2 * e];
        b[1] = (_Float16)W3[16 + kg * 4 + 2 * e + 1];
        w3v[e]     = __builtin_bit_cast(unsigned int, a);
        w3v[2 + e] = __builtin_bit_cast(unsigned int, b);
    }
    tab[14 * 64 + lane] = __builtin_bit_cast(u32x4, ai0);
    tab[15 * 64 + lane] = __builtin_bit_cast(u32x4, ai1);
    tab[16 * 64 + lane] = w3v;
}

// ---------------- main: 1 block = 2 rows = 4 waves ----------------
// MLP: verified rounds 4-8 math; epilogue via cvt_pkrtz + pk_max + dot2.
// Scan: each row split into two 256-pt half-scans (waves 0/1 row0, 2/3 row1)
// with y_255 prefix fixup through LDS.
__global__ __launch_bounds__(256, 4) void wps_kernel(
    const float* __restrict__ wp,    // (B, N, 2)
    const float* __restrict__ sww,
    const float* __restrict__ b3,
    const u32x4* __restrict__ tab,
    float* __restrict__ out)
{
    __shared__ float sLg[2][NPT];    // raw logits, 4 KB
    __shared__ float2 sY[2];         // y_255 per row

    const int t    = threadIdx.x;
    const int lane = t & 63;
    const int wv   = t >> 6;
    const int row0 = blockIdx.x * 2;

    const int nn = lane & 15;
    const int kg = lane >> 4;

    // ---- constants from table (coalesced vector loads) ----
    const half8 Wf00 = __builtin_bit_cast(half8, tab[0 * 64 + lane]);
    const half8 Wf01 = __builtin_bit_cast(half8, tab[1 * 64 + lane]);
    const half8 Wf10 = __builtin_bit_cast(half8, tab[2 * 64 + lane]);
    const half8 Wf11 = __builtin_bit_cast(half8, tab[3 * 64 + lane]);

    h2 w1pk[4][8];
    #pragma unroll
    for (int p = 0; p < 8; ++p) {
        u32x4 v = tab[(4 + p) * 64 + lane];
        #pragma unroll
        for (int e = 0; e < 4; ++e) {
            const int j = p * 4 + e;             // j = k*8 + i
            w1pk[j >> 3][j & 7] = __builtin_bit_cast(h2, (unsigned int)v[e]);
        }
    }
    h2 b1pk[8];
    {
        u32x4 v0 = tab[12 * 64 + lane];
        u32x4 v1 = tab[13 * 64 + lane];
        #pragma unroll
        for (int e = 0; e < 4; ++e) {
            b1pk[e]     = __builtin_bit_cast(h2, (unsigned int)v0[e]);
            b1pk[4 + e] = __builtin_bit_cast(h2, (unsigned int)v1[e]);
        }
    }
    const f32x4 accInit0 = __builtin_bit_cast(f32x4, tab[14 * 64 + lane]);
    const f32x4 accInit1 = __builtin_bit_cast(f32x4, tab[15 * 64 + lane]);
    h2 w3p[4];
    {
        u32x4 v = tab[16 * 64 + lane];
        #pragma unroll
        for (int e = 0; e < 4; ++e)
            w3p[e] = __builtin_bit_cast(h2, (unsigned int)v[e]);
    }

    const int seg = wv * 128;

    #pragma unroll
    for (int r = 0; r < 2; ++r) {
        const float2* P = (const float2*)(wp + (size_t)(row0 + r) * NPT * 2);

        #pragma unroll
        for (int s = 0; s < 2; ++s) {
            const int base = seg + s * 64;
            const int g    = base + lane;

            // ---- features for THIS lane's point, computed once (verified) ----
            float2 p  = P[g];
            float2 pm = P[(g > 0) ? g - 1 : 0];
            float2 pp = P[(g < NPT - 1) ? g + 1 : NPT - 1];
            float d1x, d1y;
            if (g < NPT - 1) { d1x = pp.x - p.x; d1y = pp.y - p.y; }
            else             { d1x = p.x - pm.x; d1y = p.y - pm.y; }
            float d2x = 0.f, d2y = 0.f;
            if (g >= 1 && g <= NPT - 2) {
                d2x = pp.x - 2.f * p.x + pm.x;
                d2y = pp.y - 2.f * p.y + pm.y;
            }
            h2 f01 = pkrtz(d1x, d1y);
            h2 f23 = pkrtz(d2x, d2y);
            const int u01 = __builtin_bit_cast(int, f01);
            const int u23 = __builtin_bit_cast(int, f23);

            float vkeep = 0.f;

            #pragma unroll
            for (int q = 0; q < 4; ++q) {
                // features of point base + q*16 + nn from its owner lane
                h2 r01 = __builtin_bit_cast(h2, __shfl(u01, q * 16 + nn));
                h2 r23 = __builtin_bit_cast(h2, __shfl(u23, q * 16 + nn));
                h2 f0; f0[0] = f0[1] = r01[0];
                h2 f1; f1[0] = f1[1] = r01[1];
                h2 f2; f2[0] = f2[1] = r23[0];
                h2 f3; f3[0] = f3[1] = r23[1];

                // layer 1 (verified): outputs ARE this lane's B fragments
                union { half8 v; h2 p[4]; } H0, H1;
                #pragma unroll
                for (int i = 0; i < 8; ++i) {
                    h2 h = b1pk[i];
                    h += f0 * w1pk[0][i];
                    h += f1 * w1pk[1][i];
                    h += f2 * w1pk[2][i];
                    h += f3 * w1pk[3][i];
                    h2 z; z[0] = (_Float16)0.f; z[1] = (_Float16)0.f;
                    h = __builtin_elementwise_max(h, z);
                    if (i < 4) H0.p[i] = h; else H1.p[i - 4] = h;
                }

                // layer 2 (verified swapped MFMA): A = W2^T, B = h1, C = b2
                f32x4 acc0 = accInit0;
                f32x4 acc1 = accInit1;
                acc0 = __builtin_amdgcn_mfma_f32_16x16x32_f16(Wf00, H0.v, acc0, 0, 0, 0);
                acc0 = __builtin_amdgcn_mfma_f32_16x16x32_f16(Wf10, H1.v, acc0, 0, 0, 0);
                acc1 = __builtin_amdgcn_mfma_f32_16x16x32_f16(Wf01, H0.v, acc1, 0, 0, 0);
                acc1 = __builtin_amdgcn_mfma_f32_16x16x32_f16(Wf11, H1.v, acc1, 0, 0, 0);

                // layer 3: pack->relu->dot2 against packed W3, then 2 shfl_xor
                h2 zz; zz[0] = (_Float16)0.f; zz[1] = (_Float16)0.f;
                h2 p0 = __builtin_elementwise_max(pkrtz(acc0[0], acc0[1]), zz);
                h2 p1 = __builtin_elementwise_max(pkrtz(acc0[2], acc0[3]), zz);
                h2 p2 = __builtin_elementwise_max(pkrtz(acc1[0], acc1[1]), zz);
                h2 p3 = __builtin_elementwise_max(pkrtz(acc1[2], acc1[3]), zz);
                float v = fdot2(p0, w3p[0], 0.f);
                v = fdot2(p1, w3p[1], v);
                v = fdot2(p2, w3p[2], v);
                v = fdot2(p3, w3p[3], v);
                v += __shfl_xor(v, 16);
                v += __shfl_xor(v, 32);
                vkeep = (q == kg) ? v : vkeep;
            }

            sLg[r][g] = vkeep;   // contiguous LDS store
        }
    }

    __syncthreads();

    // ---- scan: 4 waves = 2 rows x 2 half-scans with prefix fixup ----
    {
        const int rloc = wv >> 1;        // row within block
        const int half = wv & 1;         // 0: pts 0-255, 1: pts 256-511
        const int row  = row0 + rloc;
        const float2* P = (const float2*)(wp + (size_t)row * NPT * 2);
        const float bias3 = b3[0];
        const float swv   = sigmoidf_fast(sww[0]);

        const int base = half * 256 + lane * 4;   // 4 points per lane
        float wr[4];
        *reinterpret_cast<float4*>(&wr[0]) =
            *reinterpret_cast<const float4*>(&sLg[rloc][base]);

        const float4* P4 = (const float4*)P;
        float2 pts[4];
        #pragma unroll
        for (int s = 0; s < 2; ++s) {
            float4 v = P4[base / 2 + s];
            pts[2 * s].x     = v.x; pts[2 * s].y     = v.y;
            pts[2 * s + 1].x = v.z; pts[2 * s + 1].y = v.w;
        }

        float a4[4], cx4[4], cy4[4];
        float A = 1.f, Cx = 0.f, Cy = 0.f;
        #pragma unroll
        for (int i = 0; i < 4; ++i) {
            const int g = base + i;
            float a = (g == 0) ? 0.f
                               : swv * (1.f - sigmoidf_fast(wr[i] + bias3));
            float cx = (1.f - a) * pts[i].x;
            float cy = (1.f - a) * pts[i].y;
            a4[i] = a; cx4[i] = cx; cy4[i] = cy;
            Cx = fmaf(a, Cx, cx);
            Cy = fmaf(a, Cy, cy);
            A *= a;
        }
        #pragma unroll
        for (int d = 1; d < 64; d <<= 1) {
            float Ap  = __shfl_up(A, d);
            float Cpx = __shfl_up(Cx, d);
            float Cpy = __shfl_up(Cy, d);
            if (lane >= d) {
                Cx = fmaf(A, Cpx, Cx);
                Cy = fmaf(A, Cpy, Cy);
                A *= Ap;
            }
        }
        // exclusive per-lane prefix (within this half)
        float Aex  = __shfl_up(A, 1);
        float Cxex = __shfl_up(Cx, 1);
        float Cyex = __shfl_up(Cy, 1);

        float4* orow = (float4*)(out + (size_t)row * NPT * 2);

        if (half == 0) {
            float yx = (lane == 0) ? 0.f : Cxex;
            float yy = (lane == 0) ? 0.f : Cyex;
            float ox[4], oy[4];
            #pragma unroll
            for (int i = 0; i < 4; ++i) {
                yx = fmaf(a4[i], yx, cx4[i]);
                yy = fmaf(a4[i], yy, cy4[i]);
                ox[i] = yx; oy[i] = yy;
            }
            orow[base / 2]     = make_float4(ox[0], oy[0], ox[1], oy[1]);
            orow[base / 2 + 1] = make_float4(ox[2], oy[2], ox[3], oy[3]);
            if (lane == 63) { sY[rloc].x = yx; sY[rloc].y = yy; }  // y_255
        }

        __syncthreads();

        if (half == 1) {
            const float2 y255 = sY[rloc];
            float yx = (lane == 0) ? y255.x : fmaf(Aex, y255.x, Cxex);
            float yy = (lane == 0) ? y255.y : fmaf(Aex, y255.y, Cyex);
            float ox[4], oy[4];
            #pragma unroll
            for (int i = 0; i < 4; ++i) {
                yx = fmaf(a4[i], yx, cx4[i]);
                yy = fmaf(a4[i], yy, cy4[i]);
                ox[i] = yx; oy[i] = yy;
            }
            if (lane == 63) {                 // pin endpoint to original
                float2 pe = P[NPT - 1];
                ox[3] = pe.x; oy[3] = pe.y;
            }
            orow[base / 2]     = make_float4(ox[0], oy[0], ox[1], oy[1]);
            orow[base / 2 + 1] = make_float4(ox[2], oy[2], ox[3], oy[3]);
        }
    }
}

extern "C" void kernel_launch(void* const* d_in, const int* in_sizes, int n_in,
                              void* d_out, int out_size, void* d_ws, size_t ws_size,
                              hipStream_t stream) {
    const float* wp  = (const float*)d_in[0];
    const float* sww = (const float*)d_in[1];
    const float* W1  = (const float*)d_in[2];
    const float* b1  = (const float*)d_in[3];
    const float* W2  = (const float*)d_in[4];
    const float* b2  = (const float*)d_in[5];
    const float* W3  = (const float*)d_in[6];
    const float* b3  = (const float*)d_in[7];
    float* out = (float*)d_out;
    u32x4* tab = (u32x4*)d_ws;   // 17 KB used; ws is far larger

    setup_kernel<<<1, 64, 0, stream>>>(W1, b1, W2, b2, W3, tab);
    wps_kernel<<<BROWS / 2, 256, 0, stream>>>(wp, sww, b3, tab, out);
}